// Round 16
// baseline (146.834 us; speedup 1.0000x reference)
//
#include <hip/hip_runtime.h>
#include <hip/hip_bf16.h>
#include <math.h>

#define BB   16
#define CIN  256
#define HH   64
#define WW   64
#define COUT 256
#define NEXP 4
#define REDC 16
#define HW   (HH*WW)       // 4096

typedef __attribute__((ext_vector_type(8))) short short8;
typedef __attribute__((ext_vector_type(16))) float f32x16;

#define AS1 __attribute__((address_space(1)))
#define AS3 __attribute__((address_space(3)))

__device__ __forceinline__ void gld_lds16(void* lds, const void* gp) {
    __builtin_amdgcn_global_load_lds((const AS1 unsigned int*)gp,
                                     (AS3 unsigned int*)lds, 16, 0, 0);
}

// -------- K0: x (f32, [b][c][s]) -> xT (bf16, [b][hgrp][s][8c]) + pooled partials ----
__global__ __launch_bounds__(256)
void transpose_pool_kernel(const float* __restrict__ x, ushort* __restrict__ xT,
                           float* __restrict__ pp) {
    int blk = blockIdx.x;
    int sq = blk & 3;
    int chunk = (blk >> 2) & 7;
    int b = blk >> 5;
    int c0 = chunk * 32;
    int s0 = sq * 1024;
    int tid = threadIdx.x;
    const float* xb = x + ((size_t)(b * CIN + c0)) * HW;

    float psum[32];
    #pragma unroll
    for (int i = 0; i < 32; ++i) psum[i] = 0.f;

    for (int it = 0; it < 4; ++it) {
        int s = s0 + it * 256 + tid;
        unsigned int pk[16];
        #pragma unroll
        for (int p = 0; p < 16; ++p) {
            float lo = xb[(size_t)(2 * p) * HW + s];
            float hi = xb[(size_t)(2 * p + 1) * HW + s];
            psum[2 * p]     += lo;
            psum[2 * p + 1] += hi;
            asm volatile("v_cvt_pk_bf16_f32 %0, %1, %2" : "=v"(pk[p]) : "v"(lo), "v"(hi));
        }
        #pragma unroll
        for (int q = 0; q < 4; ++q) {
            ushort* dst = xT + ((size_t)(b * 32 + chunk * 4 + q) * HW + s) * 8;
            *(uint4*)dst = make_uint4(pk[q * 4], pk[q * 4 + 1], pk[q * 4 + 2], pk[q * 4 + 3]);
        }
    }

    __shared__ float red[4][32];
    int lane = tid & 63, wid = tid >> 6;
    #pragma unroll
    for (int i = 0; i < 32; ++i) {
        float v = psum[i];
        #pragma unroll
        for (int off = 32; off > 0; off >>= 1) v += __shfl_down(v, off, 64);
        if (lane == 0) red[wid][i] = v;
    }
    __syncthreads();
    if (tid < 32)
        pp[(b * 4 + sq) * 256 + c0 + tid] = red[0][tid] + red[1][tid] + red[2][tid] + red[3][tid];
}

// ---------------- K2: routing MLP -> rw[b*1024 + k*256 + c] ----------------
__global__ void route_kernel(const float* __restrict__ pp,
                             const float* __restrict__ w1, const float* __restrict__ b1,
                             const float* __restrict__ w2, const float* __restrict__ b2,
                             float* __restrict__ rw) {
    __shared__ float p_s[BB][CIN];
    __shared__ float r_s[BB][REDC];
    int tid = threadIdx.x;
    for (int i = tid; i < BB * CIN; i += 256) {
        int b = i >> 8, c = i & 255;
        p_s[b][c] = (pp[(b * 4 + 0) * 256 + c] + pp[(b * 4 + 1) * 256 + c] +
                     pp[(b * 4 + 2) * 256 + c] + pp[(b * 4 + 3) * 256 + c]) * (1.0f / HW);
    }
    __syncthreads();
    {
        int b = tid >> 4, j = tid & 15;
        float acc = b1[j];
        for (int c = 0; c < CIN; ++c) acc += p_s[b][c] * w1[j * CIN + c];
        r_s[b][j] = fmaxf(acc, 0.f);
    }
    __syncthreads();
    for (int i = tid; i < BB * NEXP * CIN; i += 256) {
        int b = i >> 10, o2 = i & 1023;
        float acc = b2[o2];
        #pragma unroll
        for (int j = 0; j < REDC; ++j) acc += r_s[b][j] * w2[o2 * REDC + j];
        rw[i] = 1.f / (1.f + expf(-acc));
    }
}

// ------- K3 v3: combined weights, flat-parallel, b-loop inside -------
__global__ __launch_bounds__(256)
void combine3_kernel(const float* __restrict__ rw,
                     const float* __restrict__ weight,
                     ushort* __restrict__ cw) {
    int blk = blockIdx.x;
    int u = blk >> 1;
    int t = (blk & 1) * 256 + threadIdx.x;    // 0..511
    int gg = u & 1;
    int v = u >> 1;
    int t9 = v % 9;
    int cu = v / 9;           // 0..63
    int chunk16 = cu & 15;
    int ot = cu >> 4;
    int o_loc = t >> 3, c8 = t & 7;
    int o = ot * 64 + o_loc;
    int c = chunk16 * 16 + gg * 8 + c8;

    __shared__ float rw_s[16][4][8];
    int tid = threadIdx.x;
    #pragma unroll
    for (int r = 0; r < 2; ++r) {
        int i = r * 256 + tid;
        if (i < 512) {
            int b = i >> 5, k = (i >> 3) & 3, cc = i & 7;
            rw_s[b][k][cc] = rw[b * 1024 + k * 256 + chunk16 * 16 + gg * 8 + cc];
        }
    }
    __syncthreads();

    float wk0 = weight[((size_t)(0 * COUT + o) * CIN + c) * 9 + t9];
    float wk1 = weight[((size_t)(1 * COUT + o) * CIN + c) * 9 + t9];
    float wk2 = weight[((size_t)(2 * COUT + o) * CIN + c) * 9 + t9];
    float wk3 = weight[((size_t)(3 * COUT + o) * CIN + c) * 9 + t9];

    size_t base = (size_t)u * 512 + t;
    #pragma unroll
    for (int b = 0; b < 16; ++b) {
        float acc = rw_s[b][0][c8] * wk0 + rw_s[b][1][c8] * wk1 +
                    rw_s[b][2][c8] * wk2 + rw_s[b][3][c8] * wk3;
        __hip_bfloat16 hv = __float2bfloat16(acc);
        cw[base + (size_t)b * 589824] = *(ushort*)&hv;
    }
}

// ---------------- K4: MFMA conv, 32x32x16, high-occupancy single-buffer ----------------
// 1024 blocks x 256 thr (4 waves). block = 64 o x 4 rows; wave = 32 o x (2 rows x 64).
// LDS 32128 B -> 5 blocks/CU (4-5 waves/SIMD): cross-block TLP hides the
// stage->drain instead of an in-block dbuf pipeline. Per wave: acc[4] (64 regs),
// 8 staging units (contiguous 1 KB each), 33 ds_read_b128 per chunk.
// Layout per block: A [t9][gg][64o][8c] at 0 (18432 B);
// X [half][r*66+cc][8c] at 18432 (12672 B; 6 rows); dummy 1 KB at 31104.
__global__ __launch_bounds__(256, 4)
void conv_mfma(const ushort* __restrict__ xT, const ushort* __restrict__ cw,
               float* __restrict__ out, const ushort* __restrict__ zp) {
    __shared__ char LDS[32128];

    int blk = blockIdx.x;
    int L = (blk & 7) * 128 + (blk >> 3);   // XCD-chunked swizzle (1024 = 8*128)
    int b  = L >> 6;          // 0..15
    int rt = (L >> 2) & 15;   // 0..15
    int ot = L & 3;
    int r0 = rt * 4, o0 = ot * 64;
    int tid = threadIdx.x;
    int lane = tid & 63, wid = tid >> 6;   // wid 0..3
    int l31 = lane & 31, h = lane >> 5;
    int og = wid & 1, rg = wid >> 1;       // wave: o-half, row-group

    f32x16 acc[4];
    #pragma unroll
    for (int f = 0; f < 4; ++f) acc[f] = (f32x16)0.f;

    const char* xTb = (const char*)(xT + (size_t)b * 32 * HW * 8);
    const ushort* Ab = cw + (size_t)((b * 4 + ot) * 16) * 9216;

    // ---- per-unit staging descriptors (uniform 8 units/wave, 30 real + 2 dummy) ----
    const char* srcb[8];
    int dsto[8];
    int strd[8];
    #pragma unroll
    for (int i = 0; i < 8; ++i) {
        int u = wid * 8 + i;
        if (u < 18) {            // A units: contiguous 1 KB each
            srcb[i] = (const char*)(Ab + (size_t)u * 512) + lane * 16;
            dsto[i] = u * 1024;
            strd[i] = 18432;
        } else if (u < 30) {     // X units: one (row, half), contiguous 1 KB
            int ux = u - 18;
            int r = ux >> 1, half = ux & 1;   // r 0..5
            int grow = r0 - 1 + r;
            bool valid = (grow >= 0 && grow < 64);
            srcb[i] = valid
                ? xTb + (size_t)(half * HW + grow * 64) * 16 + lane * 16
                : (const char*)zp + lane * 16;
            dsto[i] = 18432 + (half * 396 + r * 66 + 1) * 16;
            strd[i] = valid ? 131072 : 0;     // hgrp += 2 per chunk16
        } else {                 // dummy: keep per-wave count uniform
            srcb[i] = (const char*)zp + lane * 16;
            dsto[i] = 31104;                   // 1 KB scratch, in-bounds
            strd[i] = 0;
        }
    }

    // zero-init LDS once (X halo cols must stay 0 across all chunks)
    for (int i = tid; i < 8032; i += 256) ((unsigned int*)LDS)[i] = 0;
    __syncthreads();

    #define STAGE(CH)                                                         \
    {                                                                         \
        _Pragma("unroll")                                                     \
        for (int i = 0; i < 8; ++i)                                           \
            gld_lds16(LDS + dsto[i], srcb[i] + (size_t)(CH) * strd[i]);       \
    }

    #define LDA(T, pa)                                                        \
        pa = *(const short8*)&asb[(((T) * 2 + h) * 64 + og * 32 + l31) * 8];

    #define LDB(R, S, DJ, v)                                                  \
        v = *(const short8*)&xsb[((rg * 2 + (R)) * 66 + (S) * 32 + l31 + (DJ)) * 8];

    #define DO4(pa, v0, v1, v2, v3)                                                   \
    {                                                                                 \
        acc[0] = __builtin_amdgcn_mfma_f32_32x32x16_bf16(pa, v0, acc[0], 0, 0, 0);    \
        acc[1] = __builtin_amdgcn_mfma_f32_32x32x16_bf16(pa, v1, acc[1], 0, 0, 0);    \
        acc[2] = __builtin_amdgcn_mfma_f32_32x32x16_bf16(pa, v2, acc[2], 0, 0, 0);    \
        acc[3] = __builtin_amdgcn_mfma_f32_32x32x16_bf16(pa, v3, acc[3], 0, 0, 0);    \
    }

    // dj-group: taps DJ, DJ+3, DJ+6 share B rows (4 rows x 2 segs)
    #define GROUP(DJ)                                                         \
    {                                                                         \
        short8 x00, x01, x10, x11, x20, x21, x30, x31, pa, qa, ra;            \
        LDB(0, 0, DJ, x00) LDB(0, 1, DJ, x01)                                 \
        LDB(1, 0, DJ, x10) LDB(1, 1, DJ, x11)                                 \
        LDA(DJ, pa)                                                           \
        LDB(2, 0, DJ, x20) LDB(2, 1, DJ, x21)                                 \
        LDA((DJ) + 3, qa)                                                     \
        DO4(pa, x00, x01, x10, x11)              /* di = 0 */                 \
        LDB(3, 0, DJ, x30) LDB(3, 1, DJ, x31)                                 \
        LDA((DJ) + 6, ra)                                                     \
        DO4(qa, x10, x11, x20, x21)              /* di = 1 */                 \
        DO4(ra, x20, x21, x30, x31)              /* di = 2 */                 \
    }

    #pragma unroll 1
    for (int chunk = 0; chunk < 16; ++chunk) {
        STAGE(chunk)
        __syncthreads();     // compiler drains vmcnt before barrier

        const ushort* asb = (const ushort*)LDS;
        const ushort* xsb = (const ushort*)(LDS + 18432) + h * 3168;

        GROUP(0)
        GROUP(1)
        GROUP(2)

        __syncthreads();     // protect buffer before next chunk's staging
    }

    // ---- epilogue: C 32x32 layout: col(pos)=l31, row(o)=(j&3)+8*(j>>2)+4*h ----
    #pragma unroll
    for (int f = 0; f < 4; ++f) {
        int pos = (r0 + rg * 2 + (f >> 1)) * 64 + (f & 1) * 32 + l31;
        #pragma unroll
        for (int j = 0; j < 16; ++j) {
            int orow = (j & 3) + 8 * (j >> 2) + 4 * h;
            out[((size_t)(b * COUT + o0 + og * 32 + orow)) * HW + pos] = acc[f][j];
        }
    }
    #undef STAGE
    #undef LDA
    #undef LDB
    #undef DO4
    #undef GROUP
}

extern "C" void kernel_launch(void* const* d_in, const int* in_sizes, int n_in,
                              void* d_out, int out_size, void* d_ws, size_t ws_size,
                              hipStream_t stream) {
    const float* x      = (const float*)d_in[0];
    const float* w1     = (const float*)d_in[1];
    const float* b1     = (const float*)d_in[2];
    const float* w2     = (const float*)d_in[3];
    const float* b2     = (const float*)d_in[4];
    const float* weight = (const float*)d_in[5];
    float* out = (float*)d_out;

    float*  ws = (float*)d_ws;
    float*  pp = ws;                              // 16384 f
    float*  rw = ws + 16384;                      // 16384 f
    ushort* cw = (ushort*)(ws + 32768);           // 9437184 ushort (~18.9 MB)
    ushort* xT = (ushort*)(ws + 32768 + 4718592); // 16777216 ushort (~33.6 MB)
    ushort* zp = xT + 16777216;                   // 1024 ushort zero page (2 KB)

    hipMemsetAsync(zp, 0, 2048, stream);
    transpose_pool_kernel<<<512, 256, 0, stream>>>(x, xT, pp);
    route_kernel<<<1, 256, 0, stream>>>(pp, w1, b1, w2, b2, rw);
    combine3_kernel<<<2304, 256, 0, stream>>>(rw, weight, cw);
    conv_mfma<<<1024, 256, 0, stream>>>(xT, cw, out, zp);
}

// Round 17
// 137.313 us; speedup vs baseline: 1.0693x; 1.0693x over previous
//
#include <hip/hip_runtime.h>
#include <hip/hip_bf16.h>
#include <math.h>

#define BB   16
#define CIN  256
#define HH   64
#define WW   64
#define COUT 256
#define NEXP 4
#define REDC 16
#define HW   (HH*WW)       // 4096

typedef __attribute__((ext_vector_type(8))) short short8;
typedef __attribute__((ext_vector_type(16))) float f32x16;

#define AS1 __attribute__((address_space(1)))
#define AS3 __attribute__((address_space(3)))

__device__ __forceinline__ void gld_lds16(void* lds, const void* gp) {
    __builtin_amdgcn_global_load_lds((const AS1 unsigned int*)gp,
                                     (AS3 unsigned int*)lds, 16, 0, 0);
}

// -------- K0: x (f32, [b][c][s]) -> xT (bf16, [b][hgrp][s][8c]) + pooled partials ----
// Block 0 also zero-fills the 2 KB zero page (consumed by conv_mfma, 3 launches later).
__global__ __launch_bounds__(256)
void transpose_pool_kernel(const float* __restrict__ x, ushort* __restrict__ xT,
                           float* __restrict__ pp, ushort* __restrict__ zp) {
    int blk = blockIdx.x;
    int sq = blk & 3;
    int chunk = (blk >> 2) & 7;
    int b = blk >> 5;
    int c0 = chunk * 32;
    int s0 = sq * 1024;
    int tid = threadIdx.x;
    const float* xb = x + ((size_t)(b * CIN + c0)) * HW;

    if (blk == 0) {
        ((unsigned int*)zp)[tid] = 0;
        ((unsigned int*)zp)[tid + 256] = 0;
    }

    float psum[32];
    #pragma unroll
    for (int i = 0; i < 32; ++i) psum[i] = 0.f;

    for (int it = 0; it < 4; ++it) {
        int s = s0 + it * 256 + tid;
        unsigned int pk[16];
        #pragma unroll
        for (int p = 0; p < 16; ++p) {
            float lo = xb[(size_t)(2 * p) * HW + s];
            float hi = xb[(size_t)(2 * p + 1) * HW + s];
            psum[2 * p]     += lo;
            psum[2 * p + 1] += hi;
            asm volatile("v_cvt_pk_bf16_f32 %0, %1, %2" : "=v"(pk[p]) : "v"(lo), "v"(hi));
        }
        #pragma unroll
        for (int q = 0; q < 4; ++q) {
            ushort* dst = xT + ((size_t)(b * 32 + chunk * 4 + q) * HW + s) * 8;
            *(uint4*)dst = make_uint4(pk[q * 4], pk[q * 4 + 1], pk[q * 4 + 2], pk[q * 4 + 3]);
        }
    }

    __shared__ float red[4][32];
    int lane = tid & 63, wid = tid >> 6;
    #pragma unroll
    for (int i = 0; i < 32; ++i) {
        float v = psum[i];
        #pragma unroll
        for (int off = 32; off > 0; off >>= 1) v += __shfl_down(v, off, 64);
        if (lane == 0) red[wid][i] = v;
    }
    __syncthreads();
    if (tid < 32)
        pp[(b * 4 + sq) * 256 + c0 + tid] = red[0][tid] + red[1][tid] + red[2][tid] + red[3][tid];
}

// ---------------- K2: routing MLP -> rw[b*1024 + k*256 + c] ----------------
__global__ void route_kernel(const float* __restrict__ pp,
                             const float* __restrict__ w1, const float* __restrict__ b1,
                             const float* __restrict__ w2, const float* __restrict__ b2,
                             float* __restrict__ rw) {
    __shared__ float p_s[BB][CIN];
    __shared__ float r_s[BB][REDC];
    int tid = threadIdx.x;
    for (int i = tid; i < BB * CIN; i += 256) {
        int b = i >> 8, c = i & 255;
        p_s[b][c] = (pp[(b * 4 + 0) * 256 + c] + pp[(b * 4 + 1) * 256 + c] +
                     pp[(b * 4 + 2) * 256 + c] + pp[(b * 4 + 3) * 256 + c]) * (1.0f / HW);
    }
    __syncthreads();
    {
        int b = tid >> 4, j = tid & 15;
        float acc = b1[j];
        for (int c = 0; c < CIN; ++c) acc += p_s[b][c] * w1[j * CIN + c];
        r_s[b][j] = fmaxf(acc, 0.f);
    }
    __syncthreads();
    for (int i = tid; i < BB * NEXP * CIN; i += 256) {
        int b = i >> 10, o2 = i & 1023;
        float acc = b2[o2];
        #pragma unroll
        for (int j = 0; j < REDC; ++j) acc += r_s[b][j] * w2[o2 * REDC + j];
        rw[i] = 1.f / (1.f + expf(-acc));
    }
}

// ------- K3 v3: combined weights, flat-parallel, b-loop inside -------
__global__ __launch_bounds__(256)
void combine3_kernel(const float* __restrict__ rw,
                     const float* __restrict__ weight,
                     ushort* __restrict__ cw) {
    int blk = blockIdx.x;
    int u = blk >> 1;
    int t = (blk & 1) * 256 + threadIdx.x;    // 0..511
    int gg = u & 1;
    int v = u >> 1;
    int t9 = v % 9;
    int cu = v / 9;           // 0..63
    int chunk16 = cu & 15;
    int ot = cu >> 4;
    int o_loc = t >> 3, c8 = t & 7;
    int o = ot * 64 + o_loc;
    int c = chunk16 * 16 + gg * 8 + c8;

    __shared__ float rw_s[16][4][8];
    int tid = threadIdx.x;
    #pragma unroll
    for (int r = 0; r < 2; ++r) {
        int i = r * 256 + tid;
        if (i < 512) {
            int b = i >> 5, k = (i >> 3) & 3, cc = i & 7;
            rw_s[b][k][cc] = rw[b * 1024 + k * 256 + chunk16 * 16 + gg * 8 + cc];
        }
    }
    __syncthreads();

    float wk0 = weight[((size_t)(0 * COUT + o) * CIN + c) * 9 + t9];
    float wk1 = weight[((size_t)(1 * COUT + o) * CIN + c) * 9 + t9];
    float wk2 = weight[((size_t)(2 * COUT + o) * CIN + c) * 9 + t9];
    float wk3 = weight[((size_t)(3 * COUT + o) * CIN + c) * 9 + t9];

    size_t base = (size_t)u * 512 + t;
    #pragma unroll
    for (int b = 0; b < 16; ++b) {
        float acc = rw_s[b][0][c8] * wk0 + rw_s[b][1][c8] * wk1 +
                    rw_s[b][2][c8] * wk2 + rw_s[b][3][c8] * wk3;
        __hip_bfloat16 hv = __float2bfloat16(acc);
        cw[base + (size_t)b * 589824] = *(ushort*)&hv;
    }
}

// ---------------- K4: MFMA conv, 32x32x16, 2 blocks/CU dbuf pipeline ----------------
// Best-verified structure (R14/R15: conv 76.7-77.0 us). 512 blocks x 256 thr
// (4 waves). block = 64 o x 8 rows; 2 blocks/CU (81 KB dbuf LDS) give two
// independent barrier domains. 10 gld_lds16/wave/chunk -> vmcnt(10) counted
// pipeline; dj-grouped compute (B-row reuse); setprio wrap on compute.
__global__ __launch_bounds__(256, 2)
void conv_mfma(const ushort* __restrict__ xT, const ushort* __restrict__ cw,
               float* __restrict__ out, const ushort* __restrict__ zp) {
    __shared__ char LDS[2][40576];   // 81152 B

    int blk = blockIdx.x;
    int L = (blk & 7) * 64 + (blk >> 3);   // XCD-chunked swizzle (512 = 8*64)
    int b  = L >> 5;
    int rt = (L >> 2) & 7;
    int ot = L & 3;
    int r0 = rt * 8, o0 = ot * 64;
    int tid = threadIdx.x;
    int lane = tid & 63, wid = tid >> 6;   // wid 0..3
    int l31 = lane & 31, h = lane >> 5;

    f32x16 acc[2][4];
    #pragma unroll
    for (int mi = 0; mi < 2; ++mi)
        #pragma unroll
        for (int f = 0; f < 4; ++f) acc[mi][f] = (f32x16)0.f;

    const char* xTb = (const char*)(xT + (size_t)b * 32 * HW * 8);
    const ushort* Ab = cw + (size_t)((b * 4 + ot) * 16) * 9216;

    // ---- per-unit staging descriptors (uniform 10 units/wave) ----
    const char* srcb[10];
    int dsto[10];
    int strd[10];
    #pragma unroll
    for (int i = 0; i < 10; ++i) {
        int u = wid * 10 + i;
        if (u < 18) {            // A units: contiguous 1 KB each
            srcb[i] = (const char*)(Ab + (size_t)u * 512) + lane * 16;
            dsto[i] = u * 1024;
            strd[i] = 18432;
        } else if (u < 38) {     // X units: one (row, half), contiguous 1 KB
            int ux = u - 18;
            int r = ux >> 1, half = ux & 1;   // r 0..9
            int grow = r0 - 1 + r;
            bool valid = (grow >= 0 && grow < 64);
            srcb[i] = valid
                ? xTb + (size_t)(half * HW + grow * 64) * 16 + lane * 16
                : (const char*)zp + lane * 16;
            dsto[i] = 18432 + (half * 660 + r * 66 + 1) * 16;
            strd[i] = valid ? 131072 : 0;     // hgrp += 2 per chunk16
        } else {                 // dummy: keep per-wave count uniform
            srcb[i] = (const char*)zp + lane * 16;
            dsto[i] = 39552;                   // 1 KB scratch, in-bounds
            strd[i] = 0;
        }
    }

    char* ldsb = &LDS[0][0];

    // zero-init all of LDS once (X halo cols must stay 0 across all chunks)
    for (int i = tid; i < 20288; i += 256) ((unsigned int*)ldsb)[i] = 0;
    __syncthreads();

    #define STAGE(BUF, CH)                                                    \
    {                                                                         \
        _Pragma("unroll")                                                     \
        for (int i = 0; i < 10; ++i)                                          \
            gld_lds16(ldsb + (BUF) * 40576 + dsto[i],                         \
                      srcb[i] + (size_t)(CH) * strd[i]);                      \
    }

    #define LDA(T, pa, pb)                                                    \
        pa = *(const short8*)&asb[(((T) * 2 + h) * 64 + 0  + l31) * 8];       \
        pb = *(const short8*)&asb[(((T) * 2 + h) * 64 + 32 + l31) * 8];

    #define LDB(R, S, DJ, v)                                                  \
        v = *(const short8*)&xsb[((wid * 2 + (R)) * 66 + (S) * 32 + l31 + (DJ)) * 8];

    #define DO4(pa, pb, v0, v1, v2, v3)                                                \
    {                                                                                  \
        acc[0][0] = __builtin_amdgcn_mfma_f32_32x32x16_bf16(pa, v0, acc[0][0], 0,0,0); \
        acc[1][0] = __builtin_amdgcn_mfma_f32_32x32x16_bf16(pb, v0, acc[1][0], 0,0,0); \
        acc[0][1] = __builtin_amdgcn_mfma_f32_32x32x16_bf16(pa, v1, acc[0][1], 0,0,0); \
        acc[1][1] = __builtin_amdgcn_mfma_f32_32x32x16_bf16(pb, v1, acc[1][1], 0,0,0); \
        acc[0][2] = __builtin_amdgcn_mfma_f32_32x32x16_bf16(pa, v2, acc[0][2], 0,0,0); \
        acc[1][2] = __builtin_amdgcn_mfma_f32_32x32x16_bf16(pb, v2, acc[1][2], 0,0,0); \
        acc[0][3] = __builtin_amdgcn_mfma_f32_32x32x16_bf16(pa, v3, acc[0][3], 0,0,0); \
        acc[1][3] = __builtin_amdgcn_mfma_f32_32x32x16_bf16(pb, v3, acc[1][3], 0,0,0); \
    }

    #define GROUP(DJ)                                                         \
    {                                                                         \
        short8 x00, x01, x10, x11, x20, x21, x30, x31, pa, pb, qa, qb;        \
        LDB(0, 0, DJ, x00) LDB(0, 1, DJ, x01)                                 \
        LDB(1, 0, DJ, x10) LDB(1, 1, DJ, x11)                                 \
        LDA(DJ, pa, pb)                                                       \
        LDB(2, 0, DJ, x20) LDB(2, 1, DJ, x21)                                 \
        LDA((DJ) + 3, qa, qb)                                                 \
        DO4(pa, pb, x00, x01, x10, x11)          /* di = 0 */                 \
        LDB(3, 0, DJ, x30) LDB(3, 1, DJ, x31)                                 \
        LDA((DJ) + 6, pa, pb)                                                 \
        DO4(qa, qb, x10, x11, x20, x21)          /* di = 1 */                 \
        DO4(pa, pb, x20, x21, x30, x31)          /* di = 2 */                 \
    }

    // prologue: stage chunk 0 into buffer 0
    STAGE(0, 0)

    #pragma unroll 1
    for (int chunk = 0; chunk < 16; ++chunk) {
        int cur = chunk & 1;
        if (chunk < 15) {
            STAGE(cur ^ 1, chunk + 1)
            asm volatile("s_waitcnt vmcnt(10)" ::: "memory");
        } else {
            asm volatile("s_waitcnt vmcnt(0)" ::: "memory");
        }
        __builtin_amdgcn_s_barrier();

        const ushort* asb = (const ushort*)(ldsb + cur * 40576);
        const ushort* xsb = (const ushort*)(ldsb + cur * 40576 + 18432) + h * 5280;

        __builtin_amdgcn_s_setprio(1);
        GROUP(0)
        GROUP(1)
        GROUP(2)
        __builtin_amdgcn_s_setprio(0);

        __builtin_amdgcn_s_barrier();   // all waves done reading buf cur
    }

    // ---- epilogue: C 32x32 layout: col(pos)=l31, row(o)=(j&3)+8*(j>>2)+4*h ----
    #pragma unroll
    for (int mi = 0; mi < 2; ++mi) {
        #pragma unroll
        for (int f = 0; f < 4; ++f) {
            int pos = (r0 + wid * 2 + (f >> 1)) * 64 + (f & 1) * 32 + l31;
            #pragma unroll
            for (int j = 0; j < 16; ++j) {
                int orow = (j & 3) + 8 * (j >> 2) + 4 * h;
                out[((size_t)(b * COUT + o0 + mi * 32 + orow)) * HW + pos] = acc[mi][f][j];
            }
        }
    }
    #undef STAGE
    #undef LDA
    #undef LDB
    #undef DO4
    #undef GROUP
}

extern "C" void kernel_launch(void* const* d_in, const int* in_sizes, int n_in,
                              void* d_out, int out_size, void* d_ws, size_t ws_size,
                              hipStream_t stream) {
    const float* x      = (const float*)d_in[0];
    const float* w1     = (const float*)d_in[1];
    const float* b1     = (const float*)d_in[2];
    const float* w2     = (const float*)d_in[3];
    const float* b2     = (const float*)d_in[4];
    const float* weight = (const float*)d_in[5];
    float* out = (float*)d_out;

    float*  ws = (float*)d_ws;
    float*  pp = ws;                              // 16384 f
    float*  rw = ws + 16384;                      // 16384 f
    ushort* cw = (ushort*)(ws + 32768);           // 9437184 ushort (~18.9 MB)
    ushort* xT = (ushort*)(ws + 32768 + 4718592); // 16777216 ushort (~33.6 MB)
    ushort* zp = xT + 16777216;                   // 1024 ushort zero page (2 KB)

    transpose_pool_kernel<<<512, 256, 0, stream>>>(x, xT, pp, zp);
    route_kernel<<<1, 256, 0, stream>>>(pp, w1, b1, w2, b2, rw);
    combine3_kernel<<<2304, 256, 0, stream>>>(rw, weight, cw);
    conv_mfma<<<512, 256, 0, stream>>>(xT, cw, out, zp);
}